// Round 17
// baseline (298.388 us; speedup 1.0000x reference)
//
#include <hip/hip_runtime.h>
#include <hip/hip_bf16.h>
#include <math.h>

#define HH    48
#define CFEAT 512
#define HID   256
#define NPOS  (HH*HH)   // 2304
#define TQ    64        // queries per block
#define NEV   256       // evals per block = TQ*4

typedef __attribute__((ext_vector_type(8))) short bf16x8;
typedef __attribute__((ext_vector_type(4))) float f32x4;

static __device__ __forceinline__ unsigned short f2bf(float x) {
  unsigned int u = __float_as_uint(x);
  u += 0x7fffu + ((u >> 16) & 1u);     // RNE
  return (unsigned short)(u >> 16);
}

// packed f32x2 -> bf16x2 via v_cvt_pk_bf16_f32 (RNE)
static __device__ __forceinline__ unsigned int pk2bf(float a, float b) {
  __hip_bfloat162 h2 = __float22bfloat162_rn(make_float2(a, b));
  unsigned int u; __builtin_memcpy(&u, &h2, 4); return u;
}

// index/rel math shared (bit-exact) by Phase A and blend-area recompute
static __device__ __forceinline__ void rel_calc(float c0, float c1, int s,
                                                float& r0, float& r1,
                                                int& ir, int& ic) {
  float vx = (s & 2) ? 1.0f : -1.0f;
  float vy = (s & 1) ? 1.0f : -1.0f;
  const float RXY = (float)(1.0/48.0);
  const float CLO = (float)(-1.0 + 1e-6);
  const float CHI = (float)( 1.0 - 1e-6);
  float gx = __fadd_rn(c0, __fadd_rn(__fmul_rn(vx, RXY), 1e-6f));
  float gy = __fadd_rn(c1, __fadd_rn(__fmul_rn(vy, RXY), 1e-6f));
  gx = fminf(fmaxf(gx, CLO), CHI);
  gy = fminf(fmaxf(gy, CLO), CHI);
  float xr = __fmul_rn(__fsub_rn(__fmul_rn(__fadd_rn(gx, 1.0f), 48.0f), 1.0f), 0.5f);
  float xc = __fmul_rn(__fsub_rn(__fmul_rn(__fadd_rn(gy, 1.0f), 48.0f), 1.0f), 0.5f);
  ir = (int)rintf(xr); ir = ir < 0 ? 0 : (ir > HH-1 ? HH-1 : ir);
  ic = (int)rintf(xc); ic = ic < 0 ? 0 : (ic > HH-1 ? HH-1 : ic);
  const float T2 = (float)(2.0/48.0);
  float qcr = __fsub_rn(__fmul_rn(__fadd_rn((float)ir, 0.5f), T2), 1.0f);
  float qcc = __fsub_rn(__fmul_rn(__fadd_rn((float)ic, 0.5f), T2), 1.0f);
  r0 = __fmul_rn(__fsub_rn(c0, qcr), 48.0f);
  r1 = __fmul_rn(__fsub_rn(c1, qcc), 48.0f);
}

// ---------------------------------------------------------------------------
// Kernel 1: P[b][pos][n] = b0[n] + sum_c feat[b][c][pos] * W0[c][n]  (fp32)
// ---------------------------------------------------------------------------
__global__ __launch_bounds__(256) void liif_precompute(
    const float* __restrict__ feat, const float* __restrict__ W0,
    const float* __restrict__ b0, float* __restrict__ P)
{
  int blk = blockIdx.x;                 // 0..1151
  int b   = blk / (NPOS/4);
  int p0  = (blk - b*(NPOS/4)) * 4;
  int n   = threadIdx.x;
  const float* f = feat + (size_t)b * CFEAT * NPOS + p0;
  float bias = b0[n];
  float a0 = bias, a1 = bias, a2 = bias, a3 = bias;
  #pragma unroll 4
  for (int c = 0; c < CFEAT; ++c) {
    float w = W0[c*HID + n];
    const float* fr = f + (size_t)c * NPOS;
    a0 += fr[0]*w; a1 += fr[1]*w; a2 += fr[2]*w; a3 += fr[3]*w;
  }
  float* Pp = P + ((size_t)b*NPOS + p0)*HID + n;
  Pp[0*HID] = a0; Pp[1*HID] = a1; Pp[2*HID] = a2; Pp[3*HID] = a3;
}

// ---------------------------------------------------------------------------
// Kernel 2: pre-permuted W image (layer stride 131072 B, chunk 16 KB) +
// W4 frag image (8 KB, outputs padded 3->16).
// ---------------------------------------------------------------------------
__global__ __launch_bounds__(256) void liif_convert(
    const float* __restrict__ W1, const float* __restrict__ W2,
    const float* __restrict__ W3, const float* __restrict__ W4,
    unsigned char* __restrict__ img, unsigned char* __restrict__ w4i)
{
  int blk = blockIdx.x, t = threadIdx.x;
  if (blk < 24) {
    int l = blk >> 3, kc = blk & 7;
    const float* W = (l == 0) ? W1 : (l == 1) ? W2 : W3;
    unsigned short* dst = (unsigned short*)(img + (size_t)blk * 16384);
    #pragma unroll 1
    for (int s = 0; s < 4; ++s) {
      int p    = t + s*256;
      int wc   = p >> 8;
      int nt   = (p >> 6) & 3;
      int lane = p & 63;
      int lr   = lane & 15, lk = lane >> 4;
      int n    = wc*64 + nt*16 + lr;
      int k0   = kc*32 + lk*8;
      #pragma unroll
      for (int j = 0; j < 8; ++j)
        dst[p*8 + j] = f2bf(W[(k0 + j)*256 + n]);
    }
  } else {
    unsigned short* dst = (unsigned short*)w4i;
    #pragma unroll
    for (int u = 0; u < 2; ++u) {
      int p    = t + u*256;             // 0..511
      int kc   = p >> 6;
      int lane = p & 63;
      int n    = lane & 15;
      int k0   = kc*32 + (lane >> 4)*8;
      #pragma unroll
      for (int j = 0; j < 8; ++j)
        dst[p*8 + j] = (n < 3) ? f2bf(W4[(k0 + j)*3 + n]) : (unsigned short)0;
    }
  }
}

// ---------------------------------------------------------------------------
// Kernel 3: fused main. 256 evals/block, 512 thr / 8 waves; wave = 64x128
// tile (4m x 2n grid): 12 b128 reads feed 32 MFMA/kstep = 384 B/MFMA.
// acc 128 AGPR @ 256-reg budget (waves_per_eu(2,2)).
// act: XOR-swizzled [256 rows][512 B] = 128 KB; W: per-kstep 16 KB dbuf DMA.
// Final 256->3 layer via MFMA. LDS = exactly 160 KiB.
// ---------------------------------------------------------------------------
// LDS map:
//   [0, 131072)       act (swizzled). After final: predp overlay (3 KB).
//   [131072, 147456)  wbuf0 (L1 chunk0 prologue; W4 image in final).
//   [147456, 163840)  wbuf1; first 5 KB = {lin_s, rel4} during Phase A/B.

#define LDSW   131072

#define MF(A, B, C) __builtin_amdgcn_mfma_f32_16x16x32_bf16((A), (B), (C), 0, 0, 0)

#define AS1(p) ((const __attribute__((address_space(1))) void*)(unsigned long long)(const void*)(p))
#define AS3(p) ((__attribute__((address_space(3))) void*)(unsigned int)(unsigned long long)(void*)(p))

// DMA one 16 KB chunk with 512 threads: 2 x 16 B per thread.
#define STAGE2(LOFF, NKC, BUF) do {                                           \
    __builtin_amdgcn_global_load_lds(                                         \
        AS1(img + (LOFF) + (NKC)*16384 + sgoff),                              \
        AS3(lds + LDSW + (BUF)*16384 + swoff), 16, 0, 0);                     \
    __builtin_amdgcn_global_load_lds(                                         \
        AS1(img + (LOFF) + (NKC)*16384 + sgoff + 8192),                       \
        AS3(lds + LDSW + (BUF)*16384 + swoff + 8192), 16, 0, 0);              \
  } while (0)

// one K=32 step: optional DMA of next chunk into other buf, 8 W + 4 act b128
// reads, 32 MFMA, barrier (vmcnt drained before s_barrier => chunk ready).
#define KSTEP32(KC, HASN, NLOFF, NKC) do {                                    \
    if (HASN) STAGE2((NLOFF), (NKC), (((KC)+1)&1));                           \
    const unsigned char* wb_ = lds + LDSW + (((KC)&1)*16384) + lwoff;         \
    bf16x8 w0_ = *(const bf16x8*)(wb_ + 0);                                   \
    bf16x8 w1_ = *(const bf16x8*)(wb_ + 1024);                                \
    bf16x8 w2_ = *(const bf16x8*)(wb_ + 2048);                                \
    bf16x8 w3_ = *(const bf16x8*)(wb_ + 3072);                                \
    bf16x8 w4_ = *(const bf16x8*)(wb_ + 4096);                                \
    bf16x8 w5_ = *(const bf16x8*)(wb_ + 5120);                                \
    bf16x8 w6_ = *(const bf16x8*)(wb_ + 6144);                                \
    bf16x8 w7_ = *(const bf16x8*)(wb_ + 7168);                                \
    const int ko_ = (((KC) << 6) ^ xb6);                                      \
    bf16x8 a0_ = *(const bf16x8*)(lds + rb0 + ko_);                           \
    bf16x8 a1_ = *(const bf16x8*)(lds + rb1 + ko_);                           \
    bf16x8 a2_ = *(const bf16x8*)(lds + rb2 + ko_);                           \
    bf16x8 a3_ = *(const bf16x8*)(lds + rb3 + ko_);                           \
    acc[0]  = MF(w0_, a0_, acc[0]);  acc[1]  = MF(w1_, a0_, acc[1]);          \
    acc[2]  = MF(w2_, a0_, acc[2]);  acc[3]  = MF(w3_, a0_, acc[3]);          \
    acc[4]  = MF(w4_, a0_, acc[4]);  acc[5]  = MF(w5_, a0_, acc[5]);          \
    acc[6]  = MF(w6_, a0_, acc[6]);  acc[7]  = MF(w7_, a0_, acc[7]);          \
    acc[8]  = MF(w0_, a1_, acc[8]);  acc[9]  = MF(w1_, a1_, acc[9]);          \
    acc[10] = MF(w2_, a1_, acc[10]); acc[11] = MF(w3_, a1_, acc[11]);         \
    acc[12] = MF(w4_, a1_, acc[12]); acc[13] = MF(w5_, a1_, acc[13]);         \
    acc[14] = MF(w6_, a1_, acc[14]); acc[15] = MF(w7_, a1_, acc[15]);         \
    acc[16] = MF(w0_, a2_, acc[16]); acc[17] = MF(w1_, a2_, acc[17]);         \
    acc[18] = MF(w2_, a2_, acc[18]); acc[19] = MF(w3_, a2_, acc[19]);         \
    acc[20] = MF(w4_, a2_, acc[20]); acc[21] = MF(w5_, a2_, acc[21]);         \
    acc[22] = MF(w6_, a2_, acc[22]); acc[23] = MF(w7_, a2_, acc[23]);         \
    acc[24] = MF(w0_, a3_, acc[24]); acc[25] = MF(w1_, a3_, acc[25]);         \
    acc[26] = MF(w2_, a3_, acc[26]); acc[27] = MF(w3_, a3_, acc[27]);         \
    acc[28] = MF(w4_, a3_, acc[28]); acc[29] = MF(w5_, a3_, acc[29]);         \
    acc[30] = MF(w6_, a3_, acc[30]); acc[31] = MF(w7_, a3_, acc[31]);         \
    __syncthreads();                                                          \
  } while (0)

// L1/L2 layer: entering, wbuf0 holds chunk0; kstep7 stages next layer's c0.
#define LAYER32(LOFF, NLOFF) do {                                             \
    _Pragma("unroll")                                                         \
    for (int i_ = 0; i_ < 32; ++i_) acc[i_] = (f32x4){0.f, 0.f, 0.f, 0.f};    \
    KSTEP32(0, 1, (LOFF), 1); KSTEP32(1, 1, (LOFF), 2);                       \
    KSTEP32(2, 1, (LOFF), 3); KSTEP32(3, 1, (LOFF), 4);                       \
    KSTEP32(4, 1, (LOFF), 5); KSTEP32(5, 1, (LOFF), 6);                       \
    KSTEP32(6, 1, (LOFF), 7); KSTEP32(7, 1, (NLOFF), 0);                      \
  } while (0)

// bias+relu -> bf16 writeback into swizzled act via cvt_pk (no barrier)
#define LAYER_WB(BIAS) do {                                                   \
    _Pragma("unroll")                                                         \
    for (int nt_ = 0; nt_ < 8; ++nt_) {                                       \
      f32x4 bv_ = *(const f32x4*)&(BIAS)[nW + nt_*16 + lk*4];                 \
      const int cb_ = (cwb + nt_*32) ^ xwb;                                   \
      _Pragma("unroll")                                                       \
      for (int mt_ = 0; mt_ < 4; ++mt_) {                                     \
        f32x4 a_ = acc[mt_*8 + nt_];                                          \
        unsigned int lo_ = pk2bf(fmaxf(a_[0] + bv_[0], 0.f),                  \
                                 fmaxf(a_[1] + bv_[1], 0.f));                 \
        unsigned int hi_ = pk2bf(fmaxf(a_[2] + bv_[2], 0.f),                  \
                                 fmaxf(a_[3] + bv_[3], 0.f));                 \
        *(uint2*)(lds + ((m0 + mt_*16 + lr) << 9) + cb_) = make_uint2(lo_, hi_); \
      }                                                                       \
    }                                                                         \
  } while (0)

__global__ __launch_bounds__(512, 2)
__attribute__((amdgpu_waves_per_eu(2, 2)))
void liif_main(
    const float* __restrict__ coord, const float* __restrict__ cell,
    const float* __restrict__ P,  const float* __restrict__ W0,
    const unsigned char* __restrict__ img,
    const unsigned char* __restrict__ w4i,
    const float* __restrict__ b1, const float* __restrict__ b2,
    const float* __restrict__ b3, const float* __restrict__ b4,
    float* __restrict__ out)
{
  __shared__ __align__(16) unsigned char lds[163840];
  int*   lin_s = (int*)  (lds + 147456);        // overlay in wbuf1 (pre-GEMM)
  f32x4* rel4  = (f32x4*)(lds + 147456 + 1024);
  float* predp = (float*)lds;                   // [256 m][3 o] = 3 KB

  const int t   = threadIdx.x;
  const int blk = blockIdx.x;
  const int b   = blk >> 10;            // 1024 blocks per batch
  const int q0  = (blk & 1023) * TQ;

  const int lane = t & 63;
  const int w    = t >> 6;              // 0..7
  const int m0   = (w >> 1) * 64;       // wave row base (0/64/128/192)
  const int nW   = (w & 1) * 128;       // wave col base (0/128)
  const int lr   = lane & 15;
  const int lk   = lane >> 4;

  // DMA staging offsets (per-lane global; wave-uniform LDS base)
  const size_t sgoff = (size_t)t * 16;
  const int    swoff = w * 1024;

  // W-read base: lane-ordered image, frag j at +j*1024 (conflict-free)
  const int lwoff = (w & 1)*8192 + lane*16;
  // act-read bases (swizzle: colbyte ^ ((row&7)<<4), split into xl | xb6)
  const int xl  = (lr & 3) << 4;
  const int xb6 = ((lr >> 2) & 1) << 6;
  const int rb0 = ((m0 +  0 + lr) << 9) + ((lk << 4) ^ xl);
  const int rb1 = ((m0 + 16 + lr) << 9) + ((lk << 4) ^ xl);
  const int rb2 = ((m0 + 32 + lr) << 9) + ((lk << 4) ^ xl);
  const int rb3 = ((m0 + 48 + lr) << 9) + ((lk << 4) ^ xl);
  // writeback constants
  const int cwb = (w & 1)*256 + lk*8;
  const int xwb = (lr & 7) << 4;

  // ---- Phase A: indices + packed rel coords into wbuf1-overlay misc -------
  if (t < NEV) {
    const int e = t;
    const int q = q0 + (e >> 2);
    const int s = e & 3;                // [(-1,-1),(-1,1),(1,-1),(1,1)]
    const size_t cbase = (((size_t)b << 16) + q) * 2;
    float c0 = coord[cbase + 0];
    float c1 = coord[cbase + 1];
    float r0, r1; int ir, ic;
    rel_calc(c0, c1, s, r0, r1, ir, ic);
    lin_s[e] = ir*HH + ic;
    rel4[e] = (f32x4){r0, r1,
                      __fmul_rn(cell[cbase + 0], 48.0f),
                      __fmul_rn(cell[cbase + 1], 48.0f)};
  }
  __syncthreads();

  // issue L1 chunk0 DMA early (hides under Phase B; drained at its barrier)
  STAGE2(0, 0, 0);

  // ---- Phase B: h0 -> swizzled act. Wave = 32 rows; thread = 4 cols -------
  {
    const int cg = lane;                // col quad: cols cg*4..+3
    const float* w0t = W0 + (size_t)512*HID + cg*4;
    f32x4 wr0 = *(const f32x4*)(w0t);
    f32x4 wr1 = *(const f32x4*)(w0t + 256);
    f32x4 wr2 = *(const f32x4*)(w0t + 512);
    f32x4 wr3 = *(const f32x4*)(w0t + 768);
    const float* Pb = P + (size_t)b * NPOS * HID + cg*4;
    const int wb = cg * 8;              // byte col of this quad
    #pragma unroll 2
    for (int i = 0; i < 32; ++i) {
      const int e = w*32 + i;
      const int lin = lin_s[e];         // dword broadcast
      f32x4 rel = rel4[e];              // b128 broadcast
      f32x4 pv = *(const f32x4*)(Pb + (size_t)lin*HID);   // coalesced 1KB/row
      float v0 = pv[0] + rel[0]*wr0[0] + rel[1]*wr1[0] + rel[2]*wr2[0] + rel[3]*wr3[0];
      float v1 = pv[1] + rel[0]*wr0[1] + rel[1]*wr1[1] + rel[2]*wr2[1] + rel[3]*wr3[1];
      float v2 = pv[2] + rel[0]*wr0[2] + rel[1]*wr1[2] + rel[2]*wr2[2] + rel[3]*wr3[2];
      float v3 = pv[3] + rel[0]*wr0[3] + rel[1]*wr1[3] + rel[2]*wr2[3] + rel[3]*wr3[3];
      unsigned int lo = pk2bf(fmaxf(v0, 0.f), fmaxf(v1, 0.f));
      unsigned int hi = pk2bf(fmaxf(v2, 0.f), fmaxf(v3, 0.f));
      *(uint2*)(lds + (e << 9) + (wb ^ ((e & 7) << 4))) = make_uint2(lo, hi);
    }
  }
  __syncthreads();                      // act ready; misc read done; c0 staged

  f32x4 acc[32];
  // ---- Layer 1 -------------------------------------------------------------
  LAYER32(0, 131072);                   // kstep7 stages L2.c0 -> wbuf0
  LAYER_WB(b1);
  __syncthreads();                      // act visible

  // ---- Layer 2 -------------------------------------------------------------
  LAYER32(131072, 262144);              // kstep7 stages L3.c0 -> wbuf0
  LAYER_WB(b2);
  __syncthreads();

  // ---- Layer 3 (kstep7 stages W4 frag image into wbuf0) -------------------
  {
    #pragma unroll
    for (int i_ = 0; i_ < 32; ++i_) acc[i_] = (f32x4){0.f, 0.f, 0.f, 0.f};
    KSTEP32(0, 1, 262144, 1); KSTEP32(1, 1, 262144, 2);
    KSTEP32(2, 1, 262144, 3); KSTEP32(3, 1, 262144, 4);
    KSTEP32(4, 1, 262144, 5); KSTEP32(5, 1, 262144, 6);
    KSTEP32(6, 1, 262144, 7);
    __builtin_amdgcn_global_load_lds(AS1(w4i + sgoff),
                                     AS3(lds + LDSW + swoff), 16, 0, 0);
    KSTEP32(7, 0, 0, 0);                // barrier drains W4 DMA
  }
  LAYER_WB(b3);                         // h3 -> act (bf16, relu)
  __syncthreads();                      // act visible to all waves

  // ---- final 256->16(3) layer via MFMA: wave w owns rows w*32..+31 --------
  {
    f32x4 acc4a = (f32x4){0.f, 0.f, 0.f, 0.f};
    f32x4 acc4b = (f32x4){0.f, 0.f, 0.f, 0.f};
    const int fr0 = ((w*32)      + lr) << 9;
    const int fr1 = ((w*32 + 16) + lr) << 9;
    #pragma unroll
    for (int kc = 0; kc < 8; ++kc) {
      bf16x8 wf = *(const bf16x8*)(lds + LDSW + kc*1024 + lane*16);
      const int ko = ((kc << 6) ^ xb6) + ((lk << 4) ^ xl);
      bf16x8 afa = *(const bf16x8*)(lds + fr0 + ko);
      bf16x8 afb = *(const bf16x8*)(lds + fr1 + ko);
      acc4a = MF(wf, afa, acc4a);
      acc4b = MF(wf, afb, acc4b);
    }
    __syncthreads();                    // all act reads done (predp overlay)
    if (lk == 0) {                      // lane holds pred[m][o=j]
      float* pa = predp + (w*32 + lr)*3;
      float* pb = predp + (w*32 + 16 + lr)*3;
      pa[0] = acc4a[0] + b4[0]; pa[1] = acc4a[1] + b4[1]; pa[2] = acc4a[2] + b4[2];
      pb[0] = acc4b[0] + b4[0]; pb[1] = acc4b[1] + b4[1]; pb[2] = acc4b[2] + b4[2];
    }
  }
  __syncthreads();

  // ---- blend: w[s] = area[3-s]/tot -----------------------------------------
  if (t < TQ*3) {
    const int q = t / 3, o = t - (t/3)*3;
    const int eb = q*4;
    const size_t cbase = (((size_t)b << 16) + (q0 + q)) * 2;
    float c0 = coord[cbase + 0];
    float c1 = coord[cbase + 1];
    float ar[4];
    #pragma unroll
    for (int s = 0; s < 4; ++s) {
      float r0, r1; int ir, ic;
      rel_calc(c0, c1, s, r0, r1, ir, ic);
      ar[s] = __fadd_rn(fabsf(__fmul_rn(r0, r1)), 1e-9f);
    }
    float p0 = predp[(eb+0)*3 + o];
    float p1 = predp[(eb+1)*3 + o];
    float p2 = predp[(eb+2)*3 + o];
    float p3 = predp[(eb+3)*3 + o];
    float tot = ((ar[0] + ar[1]) + ar[2]) + ar[3];
    float rv = (p0*ar[3] + p1*ar[2] + p2*ar[1] + p3*ar[0]) / tot;
    out[(((size_t)b << 16) + (q0 + q))*3 + o] = rv;
  }
}

// ---------------------------------------------------------------------------
extern "C" void kernel_launch(void* const* d_in, const int* in_sizes, int n_in,
                              void* d_out, int out_size, void* d_ws, size_t ws_size,
                              hipStream_t stream)
{
  const float* feat  = (const float*)d_in[0];
  const float* coord = (const float*)d_in[1];
  const float* cell  = (const float*)d_in[2];
  const float* W0    = (const float*)d_in[3];
  const float* b0    = (const float*)d_in[4];
  const float* W1    = (const float*)d_in[5];
  const float* b1    = (const float*)d_in[6];
  const float* W2    = (const float*)d_in[7];
  const float* b2    = (const float*)d_in[8];
  const float* W3    = (const float*)d_in[9];
  const float* b3    = (const float*)d_in[10];
  const float* W4    = (const float*)d_in[11];
  const float* b4    = (const float*)d_in[12];
  float* outp = (float*)d_out;

  // ws layout: P f32 [2*2304*256] = 4,718,592 B | W image 3*131072 = 393,216 B
  //            | W4 frag image 8,192 B
  float*         P    = (float*)d_ws;
  unsigned char* imgp = (unsigned char*)d_ws + 4718592;
  unsigned char* w4ip = (unsigned char*)d_ws + 4718592 + 393216;

  hipLaunchKernelGGL(liif_precompute, dim3(2*(NPOS/4)), dim3(256), 0, stream,
                     feat, W0, b0, P);
  hipLaunchKernelGGL(liif_convert, dim3(25), dim3(256), 0, stream,
                     W1, W2, W3, W4, imgp, w4ip);
  hipLaunchKernelGGL(liif_main, dim3(2048), dim3(512), 0, stream,
                     coord, cell, P, W0, imgp, w4ip, b1, b2, b3, b4, outp);
}

// Round 18
// 294.828 us; speedup vs baseline: 1.0121x; 1.0121x over previous
//
#include <hip/hip_runtime.h>
#include <hip/hip_bf16.h>
#include <math.h>

#define HH    48
#define CFEAT 512
#define HID   256
#define NPOS  (HH*HH)   // 2304
#define TQ    64        // queries per block
#define NEV   256       // evals per block = TQ*4

typedef __attribute__((ext_vector_type(8))) short bf16x8;
typedef __attribute__((ext_vector_type(4))) float f32x4;

static __device__ __forceinline__ unsigned short f2bf(float x) {
  unsigned int u = __float_as_uint(x);
  u += 0x7fffu + ((u >> 16) & 1u);     // RNE
  return (unsigned short)(u >> 16);
}

// packed f32x2 -> bf16x2 via v_cvt_pk_bf16_f32 (RNE)
static __device__ __forceinline__ unsigned int pk2bf(float a, float b) {
  __hip_bfloat162 h2 = __float22bfloat162_rn(make_float2(a, b));
  unsigned int u; __builtin_memcpy(&u, &h2, 4); return u;
}

// index/rel math shared (bit-exact) by Phase A and blend-area recompute
static __device__ __forceinline__ void rel_calc(float c0, float c1, int s,
                                                float& r0, float& r1,
                                                int& ir, int& ic) {
  float vx = (s & 2) ? 1.0f : -1.0f;
  float vy = (s & 1) ? 1.0f : -1.0f;
  const float RXY = (float)(1.0/48.0);
  const float CLO = (float)(-1.0 + 1e-6);
  const float CHI = (float)( 1.0 - 1e-6);
  float gx = __fadd_rn(c0, __fadd_rn(__fmul_rn(vx, RXY), 1e-6f));
  float gy = __fadd_rn(c1, __fadd_rn(__fmul_rn(vy, RXY), 1e-6f));
  gx = fminf(fmaxf(gx, CLO), CHI);
  gy = fminf(fmaxf(gy, CLO), CHI);
  float xr = __fmul_rn(__fsub_rn(__fmul_rn(__fadd_rn(gx, 1.0f), 48.0f), 1.0f), 0.5f);
  float xc = __fmul_rn(__fsub_rn(__fmul_rn(__fadd_rn(gy, 1.0f), 48.0f), 1.0f), 0.5f);
  ir = (int)rintf(xr); ir = ir < 0 ? 0 : (ir > HH-1 ? HH-1 : ir);
  ic = (int)rintf(xc); ic = ic < 0 ? 0 : (ic > HH-1 ? HH-1 : ic);
  const float T2 = (float)(2.0/48.0);
  float qcr = __fsub_rn(__fmul_rn(__fadd_rn((float)ir, 0.5f), T2), 1.0f);
  float qcc = __fsub_rn(__fmul_rn(__fadd_rn((float)ic, 0.5f), T2), 1.0f);
  r0 = __fmul_rn(__fsub_rn(c0, qcr), 48.0f);
  r1 = __fmul_rn(__fsub_rn(c1, qcc), 48.0f);
}

// ---------------------------------------------------------------------------
// Kernel 1: P[b][pos][n] = b0[n] + sum_c feat[b][c][pos] * W0[c][n]  (fp32)
// ---------------------------------------------------------------------------
__global__ __launch_bounds__(256) void liif_precompute(
    const float* __restrict__ feat, const float* __restrict__ W0,
    const float* __restrict__ b0, float* __restrict__ P)
{
  int blk = blockIdx.x;                 // 0..1151
  int b   = blk / (NPOS/4);
  int p0  = (blk - b*(NPOS/4)) * 4;
  int n   = threadIdx.x;
  const float* f = feat + (size_t)b * CFEAT * NPOS + p0;
  float bias = b0[n];
  float a0 = bias, a1 = bias, a2 = bias, a3 = bias;
  #pragma unroll 4
  for (int c = 0; c < CFEAT; ++c) {
    float w = W0[c*HID + n];
    const float* fr = f + (size_t)c * NPOS;
    a0 += fr[0]*w; a1 += fr[1]*w; a2 += fr[2]*w; a3 += fr[3]*w;
  }
  float* Pp = P + ((size_t)b*NPOS + p0)*HID + n;
  Pp[0*HID] = a0; Pp[1*HID] = a1; Pp[2*HID] = a2; Pp[3*HID] = a3;
}

// ---------------------------------------------------------------------------
// Kernel 2: pre-permuted W image (layer stride 131072 B, chunk 16 KB) +
// W4 frag image (8 KB, outputs padded 3->16).
// ---------------------------------------------------------------------------
__global__ __launch_bounds__(256) void liif_convert(
    const float* __restrict__ W1, const float* __restrict__ W2,
    const float* __restrict__ W3, const float* __restrict__ W4,
    unsigned char* __restrict__ img, unsigned char* __restrict__ w4i)
{
  int blk = blockIdx.x, t = threadIdx.x;
  if (blk < 24) {
    int l = blk >> 3, kc = blk & 7;
    const float* W = (l == 0) ? W1 : (l == 1) ? W2 : W3;
    unsigned short* dst = (unsigned short*)(img + (size_t)blk * 16384);
    #pragma unroll 1
    for (int s = 0; s < 4; ++s) {
      int p    = t + s*256;
      int wc   = p >> 8;
      int nt   = (p >> 6) & 3;
      int lane = p & 63;
      int lr   = lane & 15, lk = lane >> 4;
      int n    = wc*64 + nt*16 + lr;
      int k0   = kc*32 + lk*8;
      #pragma unroll
      for (int j = 0; j < 8; ++j)
        dst[p*8 + j] = f2bf(W[(k0 + j)*256 + n]);
    }
  } else {
    unsigned short* dst = (unsigned short*)w4i;
    #pragma unroll
    for (int u = 0; u < 2; ++u) {
      int p    = t + u*256;             // 0..511
      int kc   = p >> 6;
      int lane = p & 63;
      int n    = lane & 15;
      int k0   = kc*32 + (lane >> 4)*8;
      #pragma unroll
      for (int j = 0; j < 8; ++j)
        dst[p*8 + j] = (n < 3) ? f2bf(W4[(k0 + j)*3 + n]) : (unsigned short)0;
    }
  }
}

// ---------------------------------------------------------------------------
// Kernel 3: fused main. 256 evals/block, 512 thr / 8 waves; wave = 64x128
// tile (4m x 2n): 12 b128 reads feed 32 MFMA/kstep = 384 B/MFMA.
// W: per-kstep 16 KB dbuf via global_load_lds with COUNTED vmcnt(2) +
// raw s_barrier (prefetch stays in flight across barriers) + setprio(1)
// around the MFMA cluster. Real __syncthreads at phase/layer boundaries.
// Final 256->3 layer via MFMA. LDS = exactly 160 KiB.
// ---------------------------------------------------------------------------
// LDS map:
//   [0, 131072)       act (swizzled). After final: predp overlay (3 KB).
//   [131072, 147456)  wbuf0 (L1 chunk0 prologue; W4 image in final).
//   [147456, 163840)  wbuf1; first 5 KB = {lin_s, rel4} during Phase A/B.

#define LDSW   131072

#define MF(A, B, C) __builtin_amdgcn_mfma_f32_16x16x32_bf16((A), (B), (C), 0, 0, 0)

#define AS1(p) ((const __attribute__((address_space(1))) void*)(unsigned long long)(const void*)(p))
#define AS3(p) ((__attribute__((address_space(3))) void*)(unsigned int)(unsigned long long)(void*)(p))

// DMA one 16 KB chunk with 512 threads: 2 x 16 B per thread.
#define STAGE2(LOFF, NKC, BUF) do {                                           \
    __builtin_amdgcn_global_load_lds(                                         \
        AS1(img + (LOFF) + (NKC)*16384 + sgoff),                              \
        AS3(lds + LDSW + (BUF)*16384 + swoff), 16, 0, 0);                     \
    __builtin_amdgcn_global_load_lds(                                         \
        AS1(img + (LOFF) + (NKC)*16384 + sgoff + 8192),                       \
        AS3(lds + LDSW + (BUF)*16384 + swoff + 8192), 16, 0, 0);              \
  } while (0)

// one K=32 step with counted-vmcnt pipeline:
//   issue next-chunk DMA (2 ops) -> s_waitcnt vmcnt(VMN) (waits only the
//   chunk staged one kstep ago; new ops stay in flight) -> 12 b128 reads ->
//   setprio(1) 32 MFMA setprio(0) -> raw s_barrier (no vmcnt drain).
// Buffer-overwrite safety: per-kstep barrier; each wave's reads complete
// before its barrier via the MFMA lgkmcnt dependency.
#define KSTEP32(KC, HASN, NLOFF, NKC, VMN) do {                               \
    if (HASN) STAGE2((NLOFF), (NKC), (((KC)+1)&1));                           \
    asm volatile("s_waitcnt vmcnt(" #VMN ")" ::: "memory");                   \
    __builtin_amdgcn_sched_barrier(0);                                        \
    const unsigned char* wb_ = lds + LDSW + (((KC)&1)*16384) + lwoff;         \
    bf16x8 w0_ = *(const bf16x8*)(wb_ + 0);                                   \
    bf16x8 w1_ = *(const bf16x8*)(wb_ + 1024);                                \
    bf16x8 w2_ = *(const bf16x8*)(wb_ + 2048);                                \
    bf16x8 w3_ = *(const bf16x8*)(wb_ + 3072);                                \
    bf16x8 w4_ = *(const bf16x8*)(wb_ + 4096);                                \
    bf16x8 w5_ = *(const bf16x8*)(wb_ + 5120);                                \
    bf16x8 w6_ = *(const bf16x8*)(wb_ + 6144);                                \
    bf16x8 w7_ = *(const bf16x8*)(wb_ + 7168);                                \
    const int ko_ = (((KC) << 6) ^ xb6);                                      \
    bf16x8 a0_ = *(const bf16x8*)(lds + rb0 + ko_);                           \
    bf16x8 a1_ = *(const bf16x8*)(lds + rb1 + ko_);                           \
    bf16x8 a2_ = *(const bf16x8*)(lds + rb2 + ko_);                           \
    bf16x8 a3_ = *(const bf16x8*)(lds + rb3 + ko_);                           \
    __builtin_amdgcn_s_setprio(1);                                            \
    acc[0]  = MF(w0_, a0_, acc[0]);  acc[1]  = MF(w1_, a0_, acc[1]);          \
    acc[2]  = MF(w2_, a0_, acc[2]);  acc[3]  = MF(w3_, a0_, acc[3]);          \
    acc[4]  = MF(w4_, a0_, acc[4]);  acc[5]  = MF(w5_, a0_, acc[5]);          \
    acc[6]  = MF(w6_, a0_, acc[6]);  acc[7]  = MF(w7_, a0_, acc[7]);          \
    acc[8]  = MF(w0_, a1_, acc[8]);  acc[9]  = MF(w1_, a1_, acc[9]);          \
    acc[10] = MF(w2_, a1_, acc[10]); acc[11] = MF(w3_, a1_, acc[11]);         \
    acc[12] = MF(w4_, a1_, acc[12]); acc[13] = MF(w5_, a1_, acc[13]);         \
    acc[14] = MF(w6_, a1_, acc[14]); acc[15] = MF(w7_, a1_, acc[15]);         \
    acc[16] = MF(w0_, a2_, acc[16]); acc[17] = MF(w1_, a2_, acc[17]);         \
    acc[18] = MF(w2_, a2_, acc[18]); acc[19] = MF(w3_, a2_, acc[19]);         \
    acc[20] = MF(w4_, a2_, acc[20]); acc[21] = MF(w5_, a2_, acc[21]);         \
    acc[22] = MF(w6_, a2_, acc[22]); acc[23] = MF(w7_, a2_, acc[23]);         \
    acc[24] = MF(w0_, a3_, acc[24]); acc[25] = MF(w1_, a3_, acc[25]);         \
    acc[26] = MF(w2_, a3_, acc[26]); acc[27] = MF(w3_, a3_, acc[27]);         \
    acc[28] = MF(w4_, a3_, acc[28]); acc[29] = MF(w5_, a3_, acc[29]);         \
    acc[30] = MF(w6_, a3_, acc[30]); acc[31] = MF(w7_, a3_, acc[31]);         \
    __builtin_amdgcn_s_setprio(0);                                            \
    __builtin_amdgcn_sched_barrier(0);                                        \
    __builtin_amdgcn_s_barrier();                                             \
    __builtin_amdgcn_sched_barrier(0);                                        \
  } while (0)

// L1/L2 layer: entering, wbuf0 holds chunk0; kstep7 stages next layer's c0.
#define LAYER32(LOFF, NLOFF) do {                                             \
    _Pragma("unroll")                                                         \
    for (int i_ = 0; i_ < 32; ++i_) acc[i_] = (f32x4){0.f, 0.f, 0.f, 0.f};    \
    KSTEP32(0, 1, (LOFF), 1, 2); KSTEP32(1, 1, (LOFF), 2, 2);                 \
    KSTEP32(2, 1, (LOFF), 3, 2); KSTEP32(3, 1, (LOFF), 4, 2);                 \
    KSTEP32(4, 1, (LOFF), 5, 2); KSTEP32(5, 1, (LOFF), 6, 2);                 \
    KSTEP32(6, 1, (LOFF), 7, 2); KSTEP32(7, 1, (NLOFF), 0, 2);                \
  } while (0)

// bias+relu -> bf16 writeback into swizzled act via cvt_pk (no barrier)
#define LAYER_WB(BIAS) do {                                                   \
    _Pragma("unroll")                                                         \
    for (int nt_ = 0; nt_ < 8; ++nt_) {                                       \
      f32x4 bv_ = *(const f32x4*)&(BIAS)[nW + nt_*16 + lk*4];                 \
      const int cb_ = (cwb + nt_*32) ^ xwb;                                   \
      _Pragma("unroll")                                                       \
      for (int mt_ = 0; mt_ < 4; ++mt_) {                                     \
        f32x4 a_ = acc[mt_*8 + nt_];                                          \
        unsigned int lo_ = pk2bf(fmaxf(a_[0] + bv_[0], 0.f),                  \
                                 fmaxf(a_[1] + bv_[1], 0.f));                 \
        unsigned int hi_ = pk2bf(fmaxf(a_[2] + bv_[2], 0.f),                  \
                                 fmaxf(a_[3] + bv_[3], 0.f));                 \
        *(uint2*)(lds + ((m0 + mt_*16 + lr) << 9) + cb_) = make_uint2(lo_, hi_); \
      }                                                                       \
    }                                                                         \
  } while (0)

__global__ __launch_bounds__(512, 2)
__attribute__((amdgpu_waves_per_eu(2, 2)))
void liif_main(
    const float* __restrict__ coord, const float* __restrict__ cell,
    const float* __restrict__ P,  const float* __restrict__ W0,
    const unsigned char* __restrict__ img,
    const unsigned char* __restrict__ w4i,
    const float* __restrict__ b1, const float* __restrict__ b2,
    const float* __restrict__ b3, const float* __restrict__ b4,
    float* __restrict__ out)
{
  __shared__ __align__(16) unsigned char lds[163840];
  int*   lin_s = (int*)  (lds + 147456);        // overlay in wbuf1 (pre-GEMM)
  f32x4* rel4  = (f32x4*)(lds + 147456 + 1024);
  float* predp = (float*)lds;                   // [256 m][3 o] = 3 KB

  const int t   = threadIdx.x;
  const int blk = blockIdx.x;
  const int b   = blk >> 10;            // 1024 blocks per batch
  const int q0  = (blk & 1023) * TQ;

  const int lane = t & 63;
  const int w    = t >> 6;              // 0..7
  const int m0   = (w >> 1) * 64;       // wave row base (0/64/128/192)
  const int nW   = (w & 1) * 128;       // wave col base (0/128)
  const int lr   = lane & 15;
  const int lk   = lane >> 4;

  // DMA staging offsets (per-lane global; wave-uniform LDS base)
  const size_t sgoff = (size_t)t * 16;
  const int    swoff = w * 1024;

  // W-read base: lane-ordered image, frag j at +j*1024 (conflict-free)
  const int lwoff = (w & 1)*8192 + lane*16;
  // act-read bases (swizzle: colbyte ^ ((row&7)<<4), split into xl | xb6)
  const int xl  = (lr & 3) << 4;
  const int xb6 = ((lr >> 2) & 1) << 6;
  const int rb0 = ((m0 +  0 + lr) << 9) + ((lk << 4) ^ xl);
  const int rb1 = ((m0 + 16 + lr) << 9) + ((lk << 4) ^ xl);
  const int rb2 = ((m0 + 32 + lr) << 9) + ((lk << 4) ^ xl);
  const int rb3 = ((m0 + 48 + lr) << 9) + ((lk << 4) ^ xl);
  // writeback constants
  const int cwb = (w & 1)*256 + lk*8;
  const int xwb = (lr & 7) << 4;

  // ---- Phase A: indices + packed rel coords into wbuf1-overlay misc -------
  if (t < NEV) {
    const int e = t;
    const int q = q0 + (e >> 2);
    const int s = e & 3;                // [(-1,-1),(-1,1),(1,-1),(1,1)]
    const size_t cbase = (((size_t)b << 16) + q) * 2;
    float c0 = coord[cbase + 0];
    float c1 = coord[cbase + 1];
    float r0, r1; int ir, ic;
    rel_calc(c0, c1, s, r0, r1, ir, ic);
    lin_s[e] = ir*HH + ic;
    rel4[e] = (f32x4){r0, r1,
                      __fmul_rn(cell[cbase + 0], 48.0f),
                      __fmul_rn(cell[cbase + 1], 48.0f)};
  }
  __syncthreads();

  // issue L1 chunk0 DMA early (hides under Phase B; drained at its barrier)
  STAGE2(0, 0, 0);

  // ---- Phase B: h0 -> swizzled act. Wave = 32 rows; thread = 4 cols -------
  {
    const int cg = lane;                // col quad: cols cg*4..+3
    const float* w0t = W0 + (size_t)512*HID + cg*4;
    f32x4 wr0 = *(const f32x4*)(w0t);
    f32x4 wr1 = *(const f32x4*)(w0t + 256);
    f32x4 wr2 = *(const f32x4*)(w0t + 512);
    f32x4 wr3 = *(const f32x4*)(w0t + 768);
    const float* Pb = P + (size_t)b * NPOS * HID + cg*4;
    const int wb = cg * 8;              // byte col of this quad
    #pragma unroll 2
    for (int i = 0; i < 32; ++i) {
      const int e = w*32 + i;
      const int lin = lin_s[e];         // dword broadcast
      f32x4 rel = rel4[e];              // b128 broadcast
      f32x4 pv = *(const f32x4*)(Pb + (size_t)lin*HID);   // coalesced 1KB/row
      float v0 = pv[0] + rel[0]*wr0[0] + rel[1]*wr1[0] + rel[2]*wr2[0] + rel[3]*wr3[0];
      float v1 = pv[1] + rel[0]*wr0[1] + rel[1]*wr1[1] + rel[2]*wr2[1] + rel[3]*wr3[1];
      float v2 = pv[2] + rel[0]*wr0[2] + rel[1]*wr1[2] + rel[2]*wr2[2] + rel[3]*wr3[2];
      float v3 = pv[3] + rel[0]*wr0[3] + rel[1]*wr1[3] + rel[2]*wr2[3] + rel[3]*wr3[3];
      unsigned int lo = pk2bf(fmaxf(v0, 0.f), fmaxf(v1, 0.f));
      unsigned int hi = pk2bf(fmaxf(v2, 0.f), fmaxf(v3, 0.f));
      *(uint2*)(lds + (e << 9) + (wb ^ ((e & 7) << 4))) = make_uint2(lo, hi);
    }
  }
  __syncthreads();                      // act ready; misc read done; c0 staged

  f32x4 acc[32];
  // ---- Layer 1 -------------------------------------------------------------
  LAYER32(0, 131072);                   // kstep7 stages L2.c0 -> wbuf0
  LAYER_WB(b1);
  __syncthreads();                      // act visible; L2.c0 drained

  // ---- Layer 2 -------------------------------------------------------------
  LAYER32(131072, 262144);              // kstep7 stages L3.c0 -> wbuf0
  LAYER_WB(b2);
  __syncthreads();

  // ---- Layer 3 (W4 frag image staged before kstep7; vmcnt(1) there) -------
  {
    #pragma unroll
    for (int i_ = 0; i_ < 32; ++i_) acc[i_] = (f32x4){0.f, 0.f, 0.f, 0.f};
    KSTEP32(0, 1, 262144, 1, 2); KSTEP32(1, 1, 262144, 2, 2);
    KSTEP32(2, 1, 262144, 3, 2); KSTEP32(3, 1, 262144, 4, 2);
    KSTEP32(4, 1, 262144, 5, 2); KSTEP32(5, 1, 262144, 6, 2);
    KSTEP32(6, 1, 262144, 7, 2);
    __builtin_amdgcn_global_load_lds(AS1(w4i + sgoff),
                                     AS3(lds + LDSW + swoff), 16, 0, 0);
    KSTEP32(7, 0, 0, 0, 1);             // wait chunk7 (2 oldest); w4i in flight
  }
  LAYER_WB(b3);                         // h3 -> act (bf16, relu)
  __syncthreads();                      // act visible; w4i DMA drained

  // ---- final 256->16(3) layer via MFMA: wave w owns rows w*32..+31 --------
  {
    f32x4 acc4a = (f32x4){0.f, 0.f, 0.f, 0.f};
    f32x4 acc4b = (f32x4){0.f, 0.f, 0.f, 0.f};
    const int fr0 = ((w*32)      + lr) << 9;
    const int fr1 = ((w*32 + 16) + lr) << 9;
    #pragma unroll
    for (int kc = 0; kc < 8; ++kc) {
      bf16x8 wf = *(const bf16x8*)(lds + LDSW + kc*1024 + lane*16);
      const int ko = ((kc << 6) ^ xb6) + ((lk << 4) ^ xl);
      bf16x8 afa = *(const bf16x8*)(lds + fr0 + ko);
      bf16x8 afb = *(const bf16x8*)(lds + fr1 + ko);
      acc4a = MF(wf, afa, acc4a);
      acc4b = MF(wf, afb, acc4b);
    }
    __syncthreads();                    // all act reads done (predp overlay)
    if (lk == 0) {                      // lane holds pred[m][o=j]
      float* pa = predp + (w*32 + lr)*3;
      float* pb = predp + (w*32 + 16 + lr)*3;
      pa[0] = acc4a[0] + b4[0]; pa[1] = acc4a[1] + b4[1]; pa[2] = acc4a[2] + b4[2];
      pb[0] = acc4b[0] + b4[0]; pb[1] = acc4b[1] + b4[1]; pb[2] = acc4b[2] + b4[2];
    }
  }
  __syncthreads();

  // ---- blend: w[s] = area[3-s]/tot -----------------------------------------
  if (t < TQ*3) {
    const int q = t / 3, o = t - (t/3)*3;
    const int eb = q*4;
    const size_t cbase = (((size_t)b << 16) + (q0 + q)) * 2;
    float c0 = coord[cbase + 0];
    float c1 = coord[cbase + 1];
    float ar[4];
    #pragma unroll
    for (int s = 0; s < 4; ++s) {
      float r0, r1; int ir, ic;
      rel_calc(c0, c1, s, r0, r1, ir, ic);
      ar[s] = __fadd_rn(fabsf(__fmul_rn(r0, r1)), 1e-9f);
    }
    float p0 = predp[(eb+0)*3 + o];
    float p1 = predp[(eb+1)*3 + o];
    float p2 = predp[(eb+2)*3 + o];
    float p3 = predp[(eb+3)*3 + o];
    float tot = ((ar[0] + ar[1]) + ar[2]) + ar[3];
    float rv = (p0*ar[3] + p1*ar[2] + p2*ar[1] + p3*ar[0]) / tot;
    out[(((size_t)b << 16) + (q0 + q))*3 + o] = rv;
  }
}

// ---------------------------------------------------------------------------
extern "C" void kernel_launch(void* const* d_in, const int* in_sizes, int n_in,
                              void* d_out, int out_size, void* d_ws, size_t ws_size,
                              hipStream_t stream)
{
  const float* feat  = (const float*)d_in[0];
  const float* coord = (const float*)d_in[1];
  const float* cell  = (const float*)d_in[2];
  const float* W0    = (const float*)d_in[3];
  const float* b0    = (const float*)d_in[4];
  const float* W1    = (const float*)d_in[5];
  const float* b1    = (const float*)d_in[6];
  const float* W2    = (const float*)d_in[7];
  const float* b2    = (const float*)d_in[8];
  const float* W3    = (const float*)d_in[9];
  const float* b3    = (const float*)d_in[10];
  const float* W4    = (const float*)d_in[11];
  const float* b4    = (const float*)d_in[12];
  float* outp = (float*)d_out;

  // ws layout: P f32 [2*2304*256] = 4,718,592 B | W image 3*131072 = 393,216 B
  //            | W4 frag image 8,192 B
  float*         P    = (float*)d_ws;
  unsigned char* imgp = (unsigned char*)d_ws + 4718592;
  unsigned char* w4ip = (unsigned char*)d_ws + 4718592 + 393216;

  hipLaunchKernelGGL(liif_precompute, dim3(2*(NPOS/4)), dim3(256), 0, stream,
                     feat, W0, b0, P);
  hipLaunchKernelGGL(liif_convert, dim3(25), dim3(256), 0, stream,
                     W1, W2, W3, W4, imgp, w4ip);
  hipLaunchKernelGGL(liif_main, dim3(2048), dim3(512), 0, stream,
                     coord, cell, P, W0, imgp, w4ip, b1, b2, b3, b4, outp);
}